// Round 10
// baseline (872.551 us; speedup 1.0000x reference)
//
#include <hip/hip_runtime.h>
#include <hip/hip_fp16.h>
#include <math.h>

#define TT 512
#define BB 32
#define SS 64
#define AA 8
#define DD 32
#define EPSF 1e-6f
#define SEPS (64.0f * 1e-6f)   // reference adds EPS under the 64-term i-sum
#define TS 68                  // fallback tile row stride

typedef _Float16 h2_t __attribute__((ext_vector_type(2)));
typedef __fp16   fp16v2 __attribute__((ext_vector_type(2)));  // cvt_pkrtz return type

__device__ __forceinline__ int   f2i(float x){ return __float_as_int(x); }
__device__ __forceinline__ float i2f(int x){ return __int_as_float(x); }
__device__ __forceinline__ float readlane_f(float v, int l){
  return i2f(__builtin_amdgcn_readlane(f2i(v), l));
}
__device__ __forceinline__ h2_t i2h2(int x){ return __builtin_bit_cast(h2_t, x); }
__device__ __forceinline__ h2_t u2h2(unsigned x){ return __builtin_bit_cast(h2_t, x); }
__device__ __forceinline__ __half2 h2bits(int x){ return __builtin_bit_cast(__half2, x); }
__device__ __forceinline__ int bitsh2(__half2 x){ return __builtin_bit_cast(int, x); }
// pack two floats to fp16 pair (RTZ) as a 32-bit lane word
__device__ __forceinline__ int pkrtz_i(float a, float b){
  fp16v2 p = __builtin_amdgcn_cvt_pkrtz(a, b);
  return __builtin_bit_cast(int, p);
}
template<int CTRL, int RMASK>
__device__ __forceinline__ float dpp_add(float x){
  return x + i2f(__builtin_amdgcn_update_dpp(0, f2i(x), CTRL, RMASK, 0xf, true));
}
__device__ __forceinline__ float wave_sum_dpp(float x){
  x = dpp_add<0x111, 0xf>(x);  // row_shr:1
  x = dpp_add<0x112, 0xf>(x);  // row_shr:2
  x = dpp_add<0x114, 0xf>(x);  // row_shr:4
  x = dpp_add<0x118, 0xf>(x);  // row_shr:8
  x = dpp_add<0x142, 0xa>(x);  // row_bcast:15 -> rows 1,3
  x = dpp_add<0x143, 0xc>(x);  // row_bcast:31 -> rows 2,3
  return readlane_f(x, 63);
}
// swap adjacent lanes (quad_perm [1,0,3,2]) for pair packing
__device__ __forceinline__ float dpp_xor1(float x){
  return i2f(__builtin_amdgcn_update_dpp(0, f2i(x), 0xB1, 0xf, 0xf, true));
}
__device__ __forceinline__ float wave_sum(float v){
  #pragma unroll
  for (int m = 1; m < 64; m <<= 1) v += __shfl_xor(v, m, 64);
  return v;
}
__device__ __forceinline__ float wave_max(float v){
  #pragma unroll
  for (int m = 1; m < 64; m <<= 1) v = fmaxf(v, __shfl_xor(v, m, 64));
  return v;
}
#define BARRIER() asm volatile("s_waitcnt lgkmcnt(0)\n\ts_barrier" ::: "memory")
#define LGKM0()   asm volatile("s_waitcnt lgkmcnt(0)" ::: "memory")

// fp16 pack helpers (RN rounding for stored tiles)
__device__ __forceinline__ unsigned pk2(float a, float b){
  return (unsigned)__half_as_ushort(__float2half_rn(a))
       | ((unsigned)__half_as_ushort(__float2half_rn(b)) << 16);
}

#if __has_builtin(__builtin_amdgcn_fdot2)
#define FDOT2(A, B, C) __builtin_amdgcn_fdot2((A), (B), (C), false)
#else
__device__ __forceinline__ float fdot2_emul(h2_t a, h2_t b, float c){
  return fmaf((float)a.x, (float)b.x, fmaf((float)a.y, (float)b.y, c));
}
#define FDOT2(A, B, C) fdot2_emul((A), (B), (C))
#endif

// --- kernel 0: invvar = exp(-logv), cs[s] = sum_d logv + D*log(2pi)
__global__ void prep_kernel(const float* __restrict__ logv,
                            float* __restrict__ iv, float* __restrict__ cs){
  int gid = blockIdx.x * blockDim.x + threadIdx.x;
  if (gid < SS * DD) iv[gid] = __expf(-logv[gid]);
  if (gid < SS){
    float s = 0.f;
    #pragma unroll
    for (int d = 0; d < DD; ++d) s += logv[gid * DD + d];
    cs[gid] = s + (float)DD * 1.8378770664093453f;
  }
}

// --- kernel 1: slx[t,b,s] = lx - rowmax(lx)
__global__ __launch_bounds__(256) void logpx_kernel(
    const float* __restrict__ x, const float* __restrict__ mu,
    const float* __restrict__ iv, const float* __restrict__ cs,
    float* __restrict__ slx_out){
  const int lane = threadIdx.x & 63;
  const int w = threadIdx.x >> 6;
  const int row = blockIdx.x * 4 + w;
  const float* __restrict__ xp  = x  + row * DD;
  const float* __restrict__ mup = mu + lane * DD;
  const float* __restrict__ ivp = iv + lane * DD;
  float acc = 0.f;
  #pragma unroll
  for (int d = 0; d < DD; ++d){
    float diff = xp[d] - mup[d];
    acc = fmaf(diff * diff, ivp[d], acc);
  }
  float lx = -0.5f * (acc + cs[lane]);
  float mx = wave_max(lx);
  slx_out[row * SS + lane] = lx - mx;
}

// --- kernel T: precompute row-normalized transition tiles, fp16,
// COLUMN-INTERLEAVED layout: per (t,b) slice of 4096 halves,
// h = q*512 + j*8 + e  holds  T[8q+e][j]  (q=0..7, j=0..63, e=0..7).
// Rowsum via wave-private LDS round-trip (r7, proven).
__global__ __launch_bounds__(512) void trans_kernel(
    const float* __restrict__ a, const float* __restrict__ w_base,
    const float* __restrict__ w_act, unsigned short* __restrict__ trans, int F){
  const int b  = blockIdx.x >> 4;       // 32 b  x 16 t-chunks of 32
  const int tc = blockIdx.x & 15;
  const int t0 = tc * 32;
  const int q    = threadIdx.x >> 6;    // row group (8 rows)
  const int j    = threadIdx.x & 63;    // column
  __shared__ float aS[32 * 8];
  __shared__ float red[8][8][68];       // [wave][row e][col j], padded
  if (threadIdx.x < 256)
    aS[threadIdx.x] = a[(((t0 + (threadIdx.x >> 3)) * BB) + b) * AA + (threadIdx.x & 7)];
  float wb[8], wa[8][8];
  #pragma unroll
  for (int e = 0; e < 8; ++e){
    wb[e] = w_base[(8 * q + e) * SS + j];
    #pragma unroll
    for (int k = 0; k < 8; ++k)
      wa[k][e] = w_act[(k * SS + 8 * q + e) * SS + j];
  }
  __syncthreads();
  const int er = j & 7;                 // reduction: this lane sums row er
  const int g8 = (j >> 3) * 8;          // over col chunk g8..g8+7
  int rem = F - t0;
  const int nt = (rem < 0) ? 0 : (rem < 32 ? rem : 32);
  for (int tt = 0; tt < nt; ++tt){
    float aa[8];
    #pragma unroll
    for (int k = 0; k < 8; ++k) aa[k] = aS[tt * 8 + k];
    float ev[8];
    #pragma unroll
    for (int e = 0; e < 8; ++e){
      float u = wb[e];
      #pragma unroll
      for (int k = 0; k < 8; ++k) u = fmaf(aa[k], wa[k][e], u);
      ev[e] = __expf(u);
    }
    // rowsum: scatter to LDS, gather 8-wide, 3-stage cross-group reduce
    #pragma unroll
    for (int e = 0; e < 8; ++e) red[q][e][j] = ev[e];
    LGKM0();                            // cross-lane within wave: order DS data
    float4 p0 = *(const float4*)&red[q][er][g8];
    float4 p1 = *(const float4*)&red[q][er][g8 + 4];
    float part = ((p0.x + p0.y) + (p0.z + p0.w)) + ((p1.x + p1.y) + (p1.z + p1.w));
    part += __shfl_xor(part, 8, 64);
    part += __shfl_xor(part, 16, 64);
    part += __shfl_xor(part, 32, 64);
    float ri = __builtin_amdgcn_rcpf(part);   // lane l: 1/rowsum(row l&7)
    float re[8];
    #pragma unroll
    for (int e = 0; e < 8; ++e) re[e] = readlane_f(ri, e);
    uint4 o;
    o.x = pk2(ev[0] * re[0], ev[1] * re[1]);
    o.y = pk2(ev[2] * re[2], ev[3] * re[3]);
    o.z = pk2(ev[4] * re[4], ev[5] * re[5]);
    o.w = pk2(ev[6] * re[6], ev[7] * re[7]);
    *(uint4*)(trans + ((size_t)(t0 + tt) * BB + b) * (SS * SS) + q * 512 + j * 8) = o;
  }
}

// --- kernel 2: ONE WAVE per chain, no barriers, bwd now ZERO LDS.
// fwd: 7-slot straight-line register ring (r8, proven).
// bwd: XOR-swizzled column loads (lane j loads quad q^((j>>3)&7) -> the
//      butterfly's keep-half and partner offsets become compile-time
//      constants, no selects) + in-register transpose-reduce:
//      3 packed-fp16 keep-stages (xor 32/16/8) then fp32 all-reduce
//      (xor 4/2/1) within 8-lane groups + 7-cndmask extract.
__global__ __launch_bounds__(64, 1) void scan_wave_kernel(
    const float* __restrict__ slx, const float* __restrict__ mask,
    const float* __restrict__ il, const unsigned short* __restrict__ trans,
    float* __restrict__ alpha, float* __restrict__ log_beta){
  const int lane = threadIdx.x;
  const bool is_fwd = (blockIdx.x < BB);
  const int b = is_fwd ? blockIdx.x : (blockIdx.x - BB);

#define LOADT(ARR, t) do{ \
    const uint4* p_ = (const uint4*)(trans + ((size_t)(t) * BB + b) * (SS * SS) + lane * 8); \
    _Pragma("unroll") \
    for (int q_ = 0; q_ < 8; ++q_) ARR[q_] = p_[q_ * 64]; \
  }while(0)

  if (is_fwd){
    // ================= FORWARD: 7-slot ring (r8, unchanged) =================
    uint4 A[8], B[8], C[8], D[8], E[8], F[8], G[8];
#define DOTQ(ARR, Q) \
    a0 = FDOT2(i2h2(__builtin_amdgcn_readlane(upki, 8*Q + 0)), u2h2(ARR[Q].x), a0); \
    a1 = FDOT2(i2h2(__builtin_amdgcn_readlane(upki, 8*Q + 2)), u2h2(ARR[Q].y), a1); \
    a2 = FDOT2(i2h2(__builtin_amdgcn_readlane(upki, 8*Q + 4)), u2h2(ARR[Q].z), a2); \
    a3 = FDOT2(i2h2(__builtin_amdgcn_readlane(upki, 8*Q + 6)), u2h2(ARR[Q].w), a3);
#define DOTS(ARR) \
    DOTQ(ARR,0) DOTQ(ARR,1) DOTQ(ARR,2) DOTQ(ARR,3) \
    DOTQ(ARR,4) DOTQ(ARR,5) DOTQ(ARR,6) DOTQ(ARR,7)

    LOADT(A, 0); LOADT(B, 1); LOADT(C, 2); LOADT(D, 3);
    LOADT(E, 4); LOADT(F, 5); LOADT(G, 6);
    float u = __expf(slx[b * SS + lane] + il[lane]);     // unnormalized alpha_0
    float c = __builtin_amdgcn_rcpf(wave_sum_dpp(u));
    alpha[b * SS + lane] = u * c;
    float slxn = slx[(BB + b) * SS + lane];

#define FBODY(s_, ARR, DOL, DOS) { \
    float elxc = __expf(slxn); \
    if (DOS) slxn = slx[(((s_) + 2) * BB + b) * SS + lane]; \
    float usw = dpp_xor1(u); \
    int upki = pkrtz_i(u, usw); \
    float a0 = 0.f, a1 = 0.f, a2 = 0.f, a3 = 0.f; \
    DOTS(ARR); \
    if (DOL) LOADT(ARR, (s_) + 7); \
    float S_ = (a0 + a1) + (a2 + a3); \
    u = elxc * fmaf(c, S_, SEPS); \
    c = __builtin_amdgcn_rcpf(wave_sum_dpp(u)); \
    alpha[(((s_) + 1) * BB + b) * SS + lane] = u * c; }

    for (int s = 0; s < 504; s += 7){    // bodies 0..503: load tiles 7..510
      FBODY(s + 0, A, 1, 1)
      FBODY(s + 1, B, 1, 1)
      FBODY(s + 2, C, 1, 1)
      FBODY(s + 3, D, 1, 1)
      FBODY(s + 4, E, 1, 1)
      FBODY(s + 5, F, 1, 1)
      FBODY(s + 6, G, 1, 1)
    }
    FBODY(504, A, 0, 1)
    FBODY(505, B, 0, 1)
    FBODY(506, C, 0, 1)
    FBODY(507, D, 0, 1)
    FBODY(508, E, 0, 1)
    FBODY(509, F, 0, 1)
    FBODY(510, G, 0, 0)
  } else {
    // ================= BACKWARD: register butterfly =================
    const int qx = (lane >> 3) & 7;            // quad XOR swizzle
    const bool j0 = (lane & 1) != 0;
    const bool j1 = (lane & 2) != 0;
    const bool j2 = (lane & 4) != 0;
    uint4 RA[8], RB_[8], RC[8], RD[8];
#define LOADTX(ARR, t) do{ \
    const unsigned short* bp_ = trans + ((size_t)(t) * BB + b) * (SS * SS) + lane * 8; \
    _Pragma("unroll") \
    for (int q_ = 0; q_ < 8; ++q_) ARR[q_] = *(const uint4*)(bp_ + (size_t)(q_ ^ qx) * 512); \
  }while(0)

    LOADTX(RA, TT - 2);   // tile 510 (body 0)
    LOADTX(RB_, TT - 3);  // 509 (body 1)
    LOADTX(RC, TT - 4);   // 508 (body 2)
    LOADTX(RD, TT - 5);   // 507 (body 3)
    float pcar = 1.0f;
    log_beta[((TT - 1) * BB + b) * SS + lane] = 0.f;
    float elxc = __expf(slx[((TT - 1) * BB + b) * SS + lane]);
    float sxn1 = slx[((TT - 2) * BB + b) * SS + lane];
    float sxn2 = slx[((TT - 3) * BB + b) * SS + lane];
    float mkc  = mask[(TT - 1) * BB + b];
    float mkn1 = mask[(TT - 2) * BB + b];
    float mkn2 = mask[(TT - 3) * BB + b];

#define BBODY(s_, RR, DOL, DOP) { \
    const int t_ = TT - 2 - (s_); \
    float wgt = elxc * pcar; \
    float W_ = wave_sum_dpp(wgt); \
    float rW_ = __builtin_amdgcn_rcpf(W_); \
    __half2 wh = h2bits(pkrtz_i(wgt, wgt)); \
    __half2 sv[32]; \
    _Pragma("unroll") \
    for (int q_ = 0; q_ < 8; ++q_){ \
      sv[4*q_+0] = __hmul2(h2bits((int)RR[q_].x), wh); \
      sv[4*q_+1] = __hmul2(h2bits((int)RR[q_].y), wh); \
      sv[4*q_+2] = __hmul2(h2bits((int)RR[q_].z), wh); \
      sv[4*q_+3] = __hmul2(h2bits((int)RR[q_].w), wh); \
    } \
    if (DOL) LOADTX(RR, t_ - 4); \
    _Pragma("unroll") \
    for (int k_ = 0; k_ < 16; ++k_) \
      sv[k_] = __hadd2(sv[k_], h2bits(__shfl_xor(bitsh2(sv[k_+16]), 32, 64))); \
    _Pragma("unroll") \
    for (int k_ = 0; k_ < 8; ++k_) \
      sv[k_] = __hadd2(sv[k_], h2bits(__shfl_xor(bitsh2(sv[k_+8]), 16, 64))); \
    _Pragma("unroll") \
    for (int k_ = 0; k_ < 4; ++k_) \
      sv[k_] = __hadd2(sv[k_], h2bits(__shfl_xor(bitsh2(sv[k_+4]), 8, 64))); \
    float f_[8]; \
    _Pragma("unroll") \
    for (int k_ = 0; k_ < 4; ++k_){ \
      f_[2*k_]     = __low2float(sv[k_]); \
      f_[2*k_ + 1] = __high2float(sv[k_]); \
    } \
    _Pragma("unroll") \
    for (int k_ = 0; k_ < 8; ++k_) f_[k_] += __shfl_xor(f_[k_], 4, 64); \
    _Pragma("unroll") \
    for (int k_ = 0; k_ < 8; ++k_) f_[k_] += __shfl_xor(f_[k_], 2, 64); \
    _Pragma("unroll") \
    for (int k_ = 0; k_ < 8; ++k_) f_[k_] += __shfl_xor(f_[k_], 1, 64); \
    float e0_ = j0 ? f_[1] : f_[0]; \
    float e1_ = j0 ? f_[3] : f_[2]; \
    float e2_ = j0 ? f_[5] : f_[4]; \
    float e3_ = j0 ? f_[7] : f_[6]; \
    float g0_ = j1 ? e1_ : e0_; \
    float g1_ = j1 ? e3_ : e2_; \
    float S_  = j2 ? g1_ : g0_; \
    float mcur = mkc; \
    float elxn = __expf(sxn1); \
    sxn1 = sxn2; mkc = mkn1; mkn1 = mkn2; \
    if (DOP){ \
      sxn2 = slx[((t_ - 2) * BB + b) * SS + lane]; \
      mkn2 = mask[(t_ - 2) * BB + b]; \
    } \
    float pv_ = fmaf(S_, rW_, EPSF); \
    pcar = (mcur == 1.0f) ? pv_ : 1.0f; \
    log_beta[(t_ * BB + b) * SS + lane] = __logf(pcar); \
    elxc = elxn; }

    for (int s = 0; s < 504; s += 4){
      BBODY(s + 0, RA,  1, 1)
      BBODY(s + 1, RB_, 1, 1)
      BBODY(s + 2, RC,  1, 1)
      BBODY(s + 3, RD,  1, 1)
    }
    BBODY(504, RA,  1, 1)   // loads tile 2
    BBODY(505, RB_, 1, 1)   // loads tile 1
    BBODY(506, RC,  1, 1)   // loads tile 0
    BBODY(507, RD,  0, 1)
    BBODY(508, RA,  0, 1)   // t_=2, DOP loads t_-2=0 (valid)
    BBODY(509, RB_, 0, 0)
    BBODY(510, RC,  0, 0)
  }
}

// --- kernel 2 (fallback, proven 403us version): fused scans with in-block
// tile generation. Used only if the workspace can't hold the fp16 tiles.
__global__ __launch_bounds__(768) void scan_kernel(
    const float* __restrict__ slx, const float* __restrict__ mask,
    const float* __restrict__ il, const float* __restrict__ a,
    const float* __restrict__ w_base, const float* __restrict__ w_act,
    float* __restrict__ alpha, float* __restrict__ log_beta){
  const int lane = threadIdx.x & 63;
  const int w    = threadIdx.x >> 6;
  const bool is_fwd = (blockIdx.x < BB);
  const int b = is_fwd ? blockIdx.x : (blockIdx.x - BB);

  __shared__ __align__(16) float tile[3][SS * TS];
  __shared__ float rsp[3][8][SS];
  __shared__ float fpart[2][4][SS];
  __shared__ __align__(16) float aLDS[TT * AA];
  __shared__ float mLDS[TT];

  for (int idx = threadIdx.x; idx < TT * AA; idx += 768){
    int t = idx >> 3, k = idx & 7;
    aLDS[idx] = a[(t * BB + b) * AA + k];
  }
  for (int idx = threadIdx.x; idx < TT; idx += 768)
    mLDS[idx] = mask[idx * BB + b];

  if (w >= 4){
    const int pw = w - 4;
    const int jb = pw * 8;
    float wb[8], wa[8][8];
    #pragma unroll
    for (int jj = 0; jj < 8; ++jj){
      wb[jj] = w_base[lane * SS + jb + jj];
      #pragma unroll
      for (int k = 0; k < 8; ++k)
        wa[k][jj] = w_act[(k * SS + lane) * SS + jb + jj];
    }
    float aa[8], aan[8];
    {
      const int t0 = is_fwd ? 0 : (TT - 2);
      const float* __restrict__ ap = a + (t0 * BB + b) * AA;
      #pragma unroll
      for (int k = 0; k < 8; ++k) aa[k] = ap[k];
      const int t1 = is_fwd ? 1 : (TT - 3);
      const float* __restrict__ ap1 = a + (t1 * BB + b) * AA;
      #pragma unroll
      for (int k = 0; k < 8; ++k) aan[k] = ap1[k];
    }
    {
      float ev[8]; float racc = 0.f;
      #pragma unroll
      for (int jj = 0; jj < 8; ++jj){
        float u = wb[jj];
        #pragma unroll
        for (int k = 0; k < 8; ++k) u = fmaf(aa[k], wa[k][jj], u);
        ev[jj] = __expf(u); racc += ev[jj];
      }
      *(float4*)&tile[0][lane * TS + jb]     = make_float4(ev[0],ev[1],ev[2],ev[3]);
      *(float4*)&tile[0][lane * TS + jb + 4] = make_float4(ev[4],ev[5],ev[6],ev[7]);
      rsp[0][pw][lane] = racc;
    }
    BARRIER();
    int tw = 1;
    for (int s = 0; s < TT - 1; ++s){
      if (s <= TT - 3){
        #pragma unroll
        for (int k = 0; k < 8; ++k) aa[k] = aan[k];
        if (s + 1 <= TT - 3){
          const int tn = is_fwd ? (s + 2) : (TT - 4 - s);
          #pragma unroll
          for (int k = 0; k < 8; ++k) aan[k] = aLDS[tn * AA + k];
        }
        float ev[8]; float racc = 0.f;
        #pragma unroll
        for (int jj = 0; jj < 8; ++jj){
          float u = wb[jj];
          #pragma unroll
          for (int k = 0; k < 8; ++k) u = fmaf(aa[k], wa[k][jj], u);
          ev[jj] = __expf(u); racc += ev[jj];
        }
        *(float4*)&tile[tw][lane * TS + jb]     = make_float4(ev[0],ev[1],ev[2],ev[3]);
        *(float4*)&tile[tw][lane * TS + jb + 4] = make_float4(ev[4],ev[5],ev[6],ev[7]);
        rsp[tw][pw][lane] = racc;
        tw = (tw == 2) ? 0 : tw + 1;
      }
      BARRIER();
    }
  } else if (is_fwd){
    const int wb16 = __builtin_amdgcn_readfirstlane(w * 16);
    float u = __expf(slx[b * SS + lane] + il[lane]);
    float c = __builtin_amdgcn_rcpf(wave_sum_dpp(u));
    if (w == 0) alpha[b * SS + lane] = u * c;
    float slxn = slx[(BB + b) * SS + lane];
    float elxc = 0.f;
    BARRIER();
    int ts = 0;
    for (int s = 0; s < TT - 1; ++s){
      if (s > 0){
        const int fs = (s - 1) & 1;
        float S = (fpart[fs][0][lane] + fpart[fs][1][lane])
                + (fpart[fs][2][lane] + fpart[fs][3][lane]);
        u = elxc * fmaf(c, S, SEPS);
        c = __builtin_amdgcn_rcpf(wave_sum_dpp(u));
        if (w == 0) alpha[(s * BB + b) * SS + lane] = u * c;
      }
      float rs = ((rsp[ts][0][lane] + rsp[ts][1][lane]) + (rsp[ts][2][lane] + rsp[ts][3][lane]))
               + ((rsp[ts][4][lane] + rsp[ts][5][lane]) + (rsp[ts][6][lane] + rsp[ts][7][lane]));
      float va = u * __builtin_amdgcn_rcpf(rs);
      const float* __restrict__ tp = &tile[ts][0];
      float a0 = 0.f, a1 = 0.f, a2 = 0.f, a3 = 0.f;
      #pragma unroll
      for (int r = 0; r < 16; r += 4){
        a0 = fmaf(readlane_f(va, wb16 + r    ), tp[(wb16 + r    ) * TS + lane], a0);
        a1 = fmaf(readlane_f(va, wb16 + r + 1), tp[(wb16 + r + 1) * TS + lane], a1);
        a2 = fmaf(readlane_f(va, wb16 + r + 2), tp[(wb16 + r + 2) * TS + lane], a2);
        a3 = fmaf(readlane_f(va, wb16 + r + 3), tp[(wb16 + r + 3) * TS + lane], a3);
      }
      fpart[s & 1][w][lane] = (a0 + a1) + (a2 + a3);
      elxc = __expf(slxn);
      if (s + 2 <= TT - 1) slxn = slx[((s + 2) * BB + b) * SS + lane];
      ts = (ts == 2) ? 0 : ts + 1;
      BARRIER();
    }
    {
      const int fs = (TT - 2) & 1;
      float S = (fpart[fs][0][lane] + fpart[fs][1][lane])
              + (fpart[fs][2][lane] + fpart[fs][3][lane]);
      u = elxc * fmaf(c, S, SEPS);
      c = __builtin_amdgcn_rcpf(wave_sum_dpp(u));
      if (w == 0) alpha[((TT - 1) * BB + b) * SS + lane] = u * c;
    }
  } else {
    const int wb16 = __builtin_amdgcn_readfirstlane(w * 16);
    float breg = 0.f, rWc = 1.f;
    if (w == 0) log_beta[((TT - 1) * BB + b) * SS + lane] = 0.f;
    float slxc = slx[((TT - 1) * BB + b) * SS + lane];
    float mprev = 1.f;
    BARRIER();
    int ts = 0, pts = 2;
    for (int s = 0; s < TT - 1; ++s){
      if (s > 0){
        const int fs = (s - 1) & 1;
        float eh = (fpart[fs][0][lane] + fpart[fs][1][lane])
                 + (fpart[fs][2][lane] + fpart[fs][3][lane]);
        float rsv = ((rsp[pts][0][lane] + rsp[pts][1][lane]) + (rsp[pts][2][lane] + rsp[pts][3][lane]))
                  + ((rsp[pts][4][lane] + rsp[pts][5][lane]) + (rsp[pts][6][lane] + rsp[pts][7][lane]));
        float v = __logf(fmaf(eh * __builtin_amdgcn_rcpf(rsv), rWc, EPSF));
        breg = (mprev == 1.0f) ? v : 0.0f;
        if (w == 0) log_beta[((TT - 1 - s) * BB + b) * SS + lane] = breg;
      }
      float wgt = __expf(slxc + breg);
      float W = wave_sum_dpp(wgt);
      rWc = __builtin_amdgcn_rcpf(W);
      const float* __restrict__ tp = &tile[ts][lane * TS + wb16];
      float4 e0 = *(const float4*)(tp);
      float4 e1 = *(const float4*)(tp + 4);
      float4 e2 = *(const float4*)(tp + 8);
      float4 e3 = *(const float4*)(tp + 12);
      float a0 = 0.f, a1 = 0.f, a2 = 0.f, a3 = 0.f;
      a0 = fmaf(readlane_f(wgt, wb16 + 0),  e0.x, a0);
      a1 = fmaf(readlane_f(wgt, wb16 + 1),  e0.y, a1);
      a2 = fmaf(readlane_f(wgt, wb16 + 2),  e0.z, a2);
      a3 = fmaf(readlane_f(wgt, wb16 + 3),  e0.w, a3);
      a0 = fmaf(readlane_f(wgt, wb16 + 4),  e1.x, a0);
      a1 = fmaf(readlane_f(wgt, wb16 + 5),  e1.y, a1);
      a2 = fmaf(readlane_f(wgt, wb16 + 6),  e1.z, a2);
      a3 = fmaf(readlane_f(wgt, wb16 + 7),  e1.w, a3);
      a0 = fmaf(readlane_f(wgt, wb16 + 8),  e2.x, a0);
      a1 = fmaf(readlane_f(wgt, wb16 + 9),  e2.y, a1);
      a2 = fmaf(readlane_f(wgt, wb16 + 10), e2.z, a2);
      a3 = fmaf(readlane_f(wgt, wb16 + 11), e2.w, a3);
      a0 = fmaf(readlane_f(wgt, wb16 + 12), e3.x, a0);
      a1 = fmaf(readlane_f(wgt, wb16 + 13), e3.y, a1);
      a2 = fmaf(readlane_f(wgt, wb16 + 14), e3.z, a2);
      a3 = fmaf(readlane_f(wgt, wb16 + 15), e3.w, a3);
      fpart[s & 1][w][lane] = (a0 + a1) + (a2 + a3);
      mprev = mLDS[TT - 1 - s];
      if (s <= TT - 3) slxc = slx[((TT - 2 - s) * BB + b) * SS + lane];
      pts = ts; ts = (ts == 2) ? 0 : ts + 1;
      BARRIER();
    }
    {
      const int fs = (TT - 2) & 1;
      float eh = (fpart[fs][0][lane] + fpart[fs][1][lane])
               + (fpart[fs][2][lane] + fpart[fs][3][lane]);
      float rsv = ((rsp[pts][0][lane] + rsp[pts][1][lane]) + (rsp[pts][2][lane] + rsp[pts][3][lane]))
                + ((rsp[pts][4][lane] + rsp[pts][5][lane]) + (rsp[pts][6][lane] + rsp[pts][7][lane]));
      float v = __logf(fmaf(eh * __builtin_amdgcn_rcpf(rsv), rWc, EPSF));
      breg = (mprev == 1.0f) ? v : 0.0f;
      if (w == 0) log_beta[b * SS + lane] = breg;
    }
  }
}

// --- kernel 3: q_z = softmax(log(alpha+EPS) + log_beta) over states
__global__ __launch_bounds__(256) void qz_kernel(
    const float* __restrict__ alpha, const float* __restrict__ log_beta,
    float* __restrict__ out){
  const int lane = threadIdx.x & 63;
  const int w = threadIdx.x >> 6;
  const int row = blockIdx.x * 4 + w;
  float v = __logf(alpha[row * SS + lane] + EPSF) + log_beta[row * SS + lane];
  float mx = wave_max(v);
  float e = __expf(v - mx);
  float sm = wave_sum(e);
  out[row * SS + lane] = e * __builtin_amdgcn_rcpf(sm);
}

extern "C" void kernel_launch(void* const* d_in, const int* in_sizes, int n_in,
                              void* d_out, int out_size, void* d_ws, size_t ws_size,
                              hipStream_t stream){
  const float* x      = (const float*)d_in[0];
  const float* a      = (const float*)d_in[1];
  const float* mask   = (const float*)d_in[2];
  const float* mu     = (const float*)d_in[3];
  const float* logv   = (const float*)d_in[4];
  const float* il     = (const float*)d_in[5];
  const float* w_base = (const float*)d_in[6];
  const float* w_act  = (const float*)d_in[7];
  float* out = (float*)d_out;

  float* ws = (float*)d_ws;
  const size_t TBS = (size_t)TT * BB * SS;
  float* iv       = ws;               // 2048 (+ cs, padded to 4096)
  float* cs       = ws + 2048;
  float* slx      = ws + 4096;        // TBS
  float* alpha    = slx + TBS;        // TBS
  float* log_beta = alpha + TBS;      // TBS
  unsigned short* trans = (unsigned short*)(log_beta + TBS); // fp16, col-interleaved

  // Full precompute: base (12.6 MB) + 511 slices x 256 KB = ~147 MB (fits).
  const size_t base_bytes = ((size_t)4096 + 3 * TBS) * 4;
  const size_t full_bytes = base_bytes + (size_t)(TT - 1) * BB * SS * SS * 2;

  prep_kernel<<<8, 256, 0, stream>>>(logv, iv, cs);
  logpx_kernel<<<TT * BB / 4, 256, 0, stream>>>(x, mu, iv, cs, slx);
  if (ws_size >= full_bytes){
    trans_kernel<<<512, 512, 0, stream>>>(a, w_base, w_act, trans, TT - 1);
    scan_wave_kernel<<<2 * BB, 64, 0, stream>>>(slx, mask, il, trans,
                                                alpha, log_beta);
  } else {
    scan_kernel<<<2 * BB, 768, 0, stream>>>(slx, mask, il, a, w_base, w_act,
                                            alpha, log_beta);
  }
  qz_kernel<<<TT * BB / 4, 256, 0, stream>>>(alpha, log_beta, out);
}

// Round 11
// 381.147 us; speedup vs baseline: 2.2893x; 2.2893x over previous
//
#include <hip/hip_runtime.h>
#include <hip/hip_fp16.h>
#include <math.h>

#define TT 512
#define BB 32
#define SS 64
#define AA 8
#define DD 32
#define EPSF 1e-6f
#define SEPS (64.0f * 1e-6f)   // reference adds EPS under the 64-term i-sum
#define TS 68                  // fallback tile row stride

typedef _Float16 h2_t __attribute__((ext_vector_type(2)));
typedef __fp16   fp16v2 __attribute__((ext_vector_type(2)));  // cvt_pkrtz return type

__device__ __forceinline__ int   f2i(float x){ return __float_as_int(x); }
__device__ __forceinline__ float i2f(int x){ return __int_as_float(x); }
__device__ __forceinline__ float readlane_f(float v, int l){
  return i2f(__builtin_amdgcn_readlane(f2i(v), l));
}
__device__ __forceinline__ h2_t i2h2(int x){ return __builtin_bit_cast(h2_t, x); }
__device__ __forceinline__ h2_t u2h2(unsigned x){ return __builtin_bit_cast(h2_t, x); }
// pack two floats to fp16 pair (RTZ) as a 32-bit lane word
__device__ __forceinline__ int pkrtz_i(float a, float b){
  fp16v2 p = __builtin_amdgcn_cvt_pkrtz(a, b);
  return __builtin_bit_cast(int, p);
}
template<int CTRL, int RMASK>
__device__ __forceinline__ float dpp_add(float x){
  return x + i2f(__builtin_amdgcn_update_dpp(0, f2i(x), CTRL, RMASK, 0xf, true));
}
__device__ __forceinline__ float wave_sum_dpp(float x){
  x = dpp_add<0x111, 0xf>(x);  // row_shr:1
  x = dpp_add<0x112, 0xf>(x);  // row_shr:2
  x = dpp_add<0x114, 0xf>(x);  // row_shr:4
  x = dpp_add<0x118, 0xf>(x);  // row_shr:8
  x = dpp_add<0x142, 0xa>(x);  // row_bcast:15 -> rows 1,3
  x = dpp_add<0x143, 0xc>(x);  // row_bcast:31 -> rows 2,3
  return readlane_f(x, 63);
}
// swap adjacent lanes (quad_perm [1,0,3,2]) for pair packing
__device__ __forceinline__ float dpp_xor1(float x){
  return i2f(__builtin_amdgcn_update_dpp(0, f2i(x), 0xB1, 0xf, 0xf, true));
}
__device__ __forceinline__ float wave_sum(float v){
  #pragma unroll
  for (int m = 1; m < 64; m <<= 1) v += __shfl_xor(v, m, 64);
  return v;
}
__device__ __forceinline__ float wave_max(float v){
  #pragma unroll
  for (int m = 1; m < 64; m <<= 1) v = fmaxf(v, __shfl_xor(v, m, 64));
  return v;
}
#define BARRIER() asm volatile("s_waitcnt lgkmcnt(0)\n\ts_barrier" ::: "memory")
#define LGKM0()   asm volatile("s_waitcnt lgkmcnt(0)" ::: "memory")

// fp16 pack helpers (RN rounding for stored tiles)
__device__ __forceinline__ unsigned pk2(float a, float b){
  return (unsigned)__half_as_ushort(__float2half_rn(a))
       | ((unsigned)__half_as_ushort(__float2half_rn(b)) << 16);
}

#if __has_builtin(__builtin_amdgcn_fdot2)
#define FDOT2(A, B, C) __builtin_amdgcn_fdot2((A), (B), (C), false)
#else
__device__ __forceinline__ float fdot2_emul(h2_t a, h2_t b, float c){
  return fmaf((float)a.x, (float)b.x, fmaf((float)a.y, (float)b.y, c));
}
#define FDOT2(A, B, C) fdot2_emul((A), (B), (C))
#endif

// --- kernel 1 (prep merged in): slx[t,b,s] = lx - rowmax(lx)
// Each thread computes exp(-logv)/sum(logv) inline (same math as the old
// prep_kernel, same summation order) -> one fewer kernel launch.
__global__ __launch_bounds__(256) void logpx_kernel(
    const float* __restrict__ x, const float* __restrict__ mu,
    const float* __restrict__ logv, float* __restrict__ slx_out){
  const int lane = threadIdx.x & 63;
  const int w = threadIdx.x >> 6;
  const int row = blockIdx.x * 4 + w;
  const float* __restrict__ xp  = x  + row * DD;
  const float* __restrict__ mup = mu + lane * DD;
  const float* __restrict__ lvp = logv + lane * DD;
  float acc = 0.f, csv = 0.f;
  #pragma unroll
  for (int d = 0; d < DD; ++d){
    float lv = lvp[d];
    float diff = xp[d] - mup[d];
    acc = fmaf(diff * diff, __expf(-lv), acc);
    csv += lv;
  }
  float lx = -0.5f * (acc + (csv + (float)DD * 1.8378770664093453f));
  float mx = wave_max(lx);
  slx_out[row * SS + lane] = lx - mx;
}

// --- kernel T: precompute row-normalized transition tiles, fp16,
// COLUMN-INTERLEAVED layout: per (t,b) slice of 4096 halves,
// h = q*512 + j*8 + e  holds  T[8q+e][j]  (q=0..7, j=0..63, e=0..7).
// Rowsum via wave-private LDS round-trip (r7, proven ~47us).
__global__ __launch_bounds__(512) void trans_kernel(
    const float* __restrict__ a, const float* __restrict__ w_base,
    const float* __restrict__ w_act, unsigned short* __restrict__ trans, int F){
  const int b  = blockIdx.x >> 4;       // 32 b  x 16 t-chunks of 32
  const int tc = blockIdx.x & 15;
  const int t0 = tc * 32;
  const int q    = threadIdx.x >> 6;    // row group (8 rows)
  const int j    = threadIdx.x & 63;    // column
  __shared__ float aS[32 * 8];
  __shared__ float red[8][8][68];       // [wave][row e][col j], padded
  if (threadIdx.x < 256)
    aS[threadIdx.x] = a[(((t0 + (threadIdx.x >> 3)) * BB) + b) * AA + (threadIdx.x & 7)];
  float wb[8], wa[8][8];
  #pragma unroll
  for (int e = 0; e < 8; ++e){
    wb[e] = w_base[(8 * q + e) * SS + j];
    #pragma unroll
    for (int k = 0; k < 8; ++k)
      wa[k][e] = w_act[(k * SS + 8 * q + e) * SS + j];
  }
  __syncthreads();
  const int er = j & 7;                 // reduction: this lane sums row er
  const int g8 = (j >> 3) * 8;          // over col chunk g8..g8+7
  int rem = F - t0;
  const int nt = (rem < 0) ? 0 : (rem < 32 ? rem : 32);
  for (int tt = 0; tt < nt; ++tt){
    float aa[8];
    #pragma unroll
    for (int k = 0; k < 8; ++k) aa[k] = aS[tt * 8 + k];
    float ev[8];
    #pragma unroll
    for (int e = 0; e < 8; ++e){
      float u = wb[e];
      #pragma unroll
      for (int k = 0; k < 8; ++k) u = fmaf(aa[k], wa[k][e], u);
      ev[e] = __expf(u);
    }
    // rowsum: scatter to LDS, gather 8-wide, 3-stage cross-group reduce
    #pragma unroll
    for (int e = 0; e < 8; ++e) red[q][e][j] = ev[e];
    LGKM0();                            // cross-lane within wave: order DS data
    float4 p0 = *(const float4*)&red[q][er][g8];
    float4 p1 = *(const float4*)&red[q][er][g8 + 4];
    float part = ((p0.x + p0.y) + (p0.z + p0.w)) + ((p1.x + p1.y) + (p1.z + p1.w));
    part += __shfl_xor(part, 8, 64);
    part += __shfl_xor(part, 16, 64);
    part += __shfl_xor(part, 32, 64);
    float ri = __builtin_amdgcn_rcpf(part);   // lane l: 1/rowsum(row l&7)
    float re[8];
    #pragma unroll
    for (int e = 0; e < 8; ++e) re[e] = readlane_f(ri, e);
    uint4 o;
    o.x = pk2(ev[0] * re[0], ev[1] * re[1]);
    o.y = pk2(ev[2] * re[2], ev[3] * re[3]);
    o.z = pk2(ev[4] * re[4], ev[5] * re[5]);
    o.w = pk2(ev[6] * re[6], ev[7] * re[7]);
    *(uint4*)(trans + ((size_t)(t0 + tt) * BB + b) * (SS * SS) + q * 512 + j * 8) = o;
  }
}

// --- kernel 2 (r8 revert, best measured): ONE WAVE per chain, no barriers.
// fwd: 7-slot straight-line register ring.
// bwd: LDS pair-row transpose (0 conflicts), linear-domain carry,
//      2-deep slx/mask prefetch.
__global__ __launch_bounds__(64, 1) void scan_wave_kernel(
    const float* __restrict__ slx, const float* __restrict__ mask,
    const float* __restrict__ il, const unsigned short* __restrict__ trans,
    float* __restrict__ alpha, float* __restrict__ log_beta){
  const int lane = threadIdx.x;
  const bool is_fwd = (blockIdx.x < BB);
  const int b = is_fwd ? blockIdx.x : (blockIdx.x - BB);

  // bwd transpose staging: word [p][j] = (T[2p][j], T[2p+1][j]); row stride
  // 68 dwords (272B): measured 0 bank conflicts in r6/r7/r8.
  __shared__ __align__(16) int Ltr[2][32 * 68];

#define LOADT(ARR, t) do{ \
    const uint4* p_ = (const uint4*)(trans + ((size_t)(t) * BB + b) * (SS * SS) + lane * 8); \
    _Pragma("unroll") \
    for (int q_ = 0; q_ < 8; ++q_) ARR[q_] = p_[q_ * 64]; \
  }while(0)

  if (is_fwd){
    // ================= FORWARD: 7-slot ring =================
    uint4 A[8], B[8], C[8], D[8], E[8], F[8], G[8];
#define DOTQ(ARR, Q) \
    a0 = FDOT2(i2h2(__builtin_amdgcn_readlane(upki, 8*Q + 0)), u2h2(ARR[Q].x), a0); \
    a1 = FDOT2(i2h2(__builtin_amdgcn_readlane(upki, 8*Q + 2)), u2h2(ARR[Q].y), a1); \
    a2 = FDOT2(i2h2(__builtin_amdgcn_readlane(upki, 8*Q + 4)), u2h2(ARR[Q].z), a2); \
    a3 = FDOT2(i2h2(__builtin_amdgcn_readlane(upki, 8*Q + 6)), u2h2(ARR[Q].w), a3);
#define DOTS(ARR) \
    DOTQ(ARR,0) DOTQ(ARR,1) DOTQ(ARR,2) DOTQ(ARR,3) \
    DOTQ(ARR,4) DOTQ(ARR,5) DOTQ(ARR,6) DOTQ(ARR,7)

    LOADT(A, 0); LOADT(B, 1); LOADT(C, 2); LOADT(D, 3);
    LOADT(E, 4); LOADT(F, 5); LOADT(G, 6);
    float u = __expf(slx[b * SS + lane] + il[lane]);     // unnormalized alpha_0
    float c = __builtin_amdgcn_rcpf(wave_sum_dpp(u));
    alpha[b * SS + lane] = u * c;
    float slxn = slx[(BB + b) * SS + lane];

#define FBODY(s_, ARR, DOL, DOS) { \
    float elxc = __expf(slxn); \
    if (DOS) slxn = slx[(((s_) + 2) * BB + b) * SS + lane]; \
    float usw = dpp_xor1(u); \
    int upki = pkrtz_i(u, usw); \
    float a0 = 0.f, a1 = 0.f, a2 = 0.f, a3 = 0.f; \
    DOTS(ARR); \
    if (DOL) LOADT(ARR, (s_) + 7); \
    float S_ = (a0 + a1) + (a2 + a3); \
    u = elxc * fmaf(c, S_, SEPS); \
    c = __builtin_amdgcn_rcpf(wave_sum_dpp(u)); \
    alpha[(((s_) + 1) * BB + b) * SS + lane] = u * c; }

    for (int s = 0; s < 504; s += 7){    // bodies 0..503: load tiles 7..510
      FBODY(s + 0, A, 1, 1)
      FBODY(s + 1, B, 1, 1)
      FBODY(s + 2, C, 1, 1)
      FBODY(s + 3, D, 1, 1)
      FBODY(s + 4, E, 1, 1)
      FBODY(s + 5, F, 1, 1)
      FBODY(s + 6, G, 1, 1)
    }
    FBODY(504, A, 0, 1)
    FBODY(505, B, 0, 1)
    FBODY(506, C, 0, 1)
    FBODY(507, D, 0, 1)
    FBODY(508, E, 0, 1)
    FBODY(509, F, 0, 1)
    FBODY(510, G, 0, 0)
  } else {
    // ================= BACKWARD (r7/r8-proven) =================
    uint4 R0[8], R1[8];
#define WLDS(SL, R) do{ \
    int* Lp_ = &Ltr[SL][lane]; \
    _Pragma("unroll") \
    for (int q_ = 0; q_ < 8; ++q_){ \
      Lp_[(4*q_ + 0) * 68] = (int)R[q_].x; \
      Lp_[(4*q_ + 1) * 68] = (int)R[q_].y; \
      Lp_[(4*q_ + 2) * 68] = (int)R[q_].z; \
      Lp_[(4*q_ + 3) * 68] = (int)R[q_].w; \
    } \
  }while(0)

    LOADT(R0, TT - 2);          // tile 510
    WLDS(0, R0);                // -> slot 0 (read at step 0)
    LOADT(R0, TT - 3);          // 509: write-source for step 0
    LOADT(R1, TT - 4);          // 508: write-source for step 1
    // carry state: pcar (linear-domain beta factor), elxc = exp(slx[T-1-s])
    float pcar = 1.0f;
    log_beta[((TT - 1) * BB + b) * SS + lane] = 0.f;
    float elxc = __expf(slx[((TT - 1) * BB + b) * SS + lane]);
    float sxn1 = slx[((TT - 2) * BB + b) * SS + lane];   // for step 1
    float sxn2 = slx[((TT - 3) * BB + b) * SS + lane];   // for step 2
    float mkc  = mask[(TT - 1) * BB + b];                // gate at step 0
    float mkn1 = mask[(TT - 2) * BB + b];
    float mkn2 = mask[(TT - 3) * BB + b];
    const int sel = (lane & 1) ? 0x07060302 : 0x05040100; // hi/lo half select

#define BBODY(s_, RB, DOW, DOL, DOP) { \
    const int t_ = TT - 2 - (s_); \
    int4 w4[16]; \
    { const int4* rp_ = (const int4*)&Ltr[(s_) & 1][(lane >> 1) * 68]; \
      _Pragma("unroll") \
      for (int k_ = 0; k_ < 16; ++k_) w4[k_] = rp_[k_]; } \
    float wgt = elxc * pcar; \
    float wsw = dpp_xor1(wgt); \
    int wpki = pkrtz_i(wgt, wsw); \
    float W_ = wave_sum_dpp(wgt); \
    float rW_ = __builtin_amdgcn_rcpf(W_); \
    if (DOW) WLDS(((s_) + 1) & 1, RB); \
    if (DOL) LOADT(RB, t_ - 3); \
    float mcur = mkc; \
    float elxn = __expf(sxn1); \
    sxn1 = sxn2; mkc = mkn1; mkn1 = mkn2; \
    if (DOP){ \
      sxn2 = slx[((t_ - 2) * BB + b) * SS + lane]; \
      mkn2 = mask[(t_ - 2) * BB + b]; \
    } \
    int hh[32]; const int* wd_ = (const int*)w4; \
    _Pragma("unroll") \
    for (int m_ = 0; m_ < 32; ++m_) \
      hh[m_] = (int)__builtin_amdgcn_perm((unsigned)wd_[2*m_ + 1], (unsigned)wd_[2*m_], (unsigned)sel); \
    float a0 = 0.f, a1 = 0.f, a2 = 0.f, a3 = 0.f; \
    _Pragma("unroll") \
    for (int m_ = 0; m_ < 32; m_ += 4){ \
      a0 = FDOT2(i2h2(__builtin_amdgcn_readlane(wpki, 2*m_ + 0)), i2h2(hh[m_ + 0]), a0); \
      a1 = FDOT2(i2h2(__builtin_amdgcn_readlane(wpki, 2*m_ + 2)), i2h2(hh[m_ + 1]), a1); \
      a2 = FDOT2(i2h2(__builtin_amdgcn_readlane(wpki, 2*m_ + 4)), i2h2(hh[m_ + 2]), a2); \
      a3 = FDOT2(i2h2(__builtin_amdgcn_readlane(wpki, 2*m_ + 6)), i2h2(hh[m_ + 3]), a3); \
    } \
    float S_ = (a0 + a1) + (a2 + a3); \
    float pv_ = fmaf(S_, rW_, EPSF); \
    pcar = (mcur == 1.0f) ? pv_ : 1.0f; \
    log_beta[(t_ * BB + b) * SS + lane] = __logf(pcar); \
    elxc = elxn; }

    for (int s = 0; s < 508; s += 2){
      BBODY(s + 0, R0, 1, 1, 1)
      BBODY(s + 1, R1, 1, 1, 1)
    }
    BBODY(508, R0, 1, 0, 1)   // writes tile 1
    BBODY(509, R1, 1, 0, 0)   // writes tile 0
    BBODY(510, R0, 0, 0, 0)
  }
}

// --- kernel 2 (fallback, proven 403us version): fused scans with in-block
// tile generation. Used only if the workspace can't hold the fp16 tiles.
__global__ __launch_bounds__(768) void scan_kernel(
    const float* __restrict__ slx, const float* __restrict__ mask,
    const float* __restrict__ il, const float* __restrict__ a,
    const float* __restrict__ w_base, const float* __restrict__ w_act,
    float* __restrict__ alpha, float* __restrict__ log_beta){
  const int lane = threadIdx.x & 63;
  const int w    = threadIdx.x >> 6;
  const bool is_fwd = (blockIdx.x < BB);
  const int b = is_fwd ? blockIdx.x : (blockIdx.x - BB);

  __shared__ __align__(16) float tile[3][SS * TS];
  __shared__ float rsp[3][8][SS];
  __shared__ float fpart[2][4][SS];
  __shared__ __align__(16) float aLDS[TT * AA];
  __shared__ float mLDS[TT];

  for (int idx = threadIdx.x; idx < TT * AA; idx += 768){
    int t = idx >> 3, k = idx & 7;
    aLDS[idx] = a[(t * BB + b) * AA + k];
  }
  for (int idx = threadIdx.x; idx < TT; idx += 768)
    mLDS[idx] = mask[idx * BB + b];

  if (w >= 4){
    const int pw = w - 4;
    const int jb = pw * 8;
    float wb[8], wa[8][8];
    #pragma unroll
    for (int jj = 0; jj < 8; ++jj){
      wb[jj] = w_base[lane * SS + jb + jj];
      #pragma unroll
      for (int k = 0; k < 8; ++k)
        wa[k][jj] = w_act[(k * SS + lane) * SS + jb + jj];
    }
    float aa[8], aan[8];
    {
      const int t0 = is_fwd ? 0 : (TT - 2);
      const float* __restrict__ ap = a + (t0 * BB + b) * AA;
      #pragma unroll
      for (int k = 0; k < 8; ++k) aa[k] = ap[k];
      const int t1 = is_fwd ? 1 : (TT - 3);
      const float* __restrict__ ap1 = a + (t1 * BB + b) * AA;
      #pragma unroll
      for (int k = 0; k < 8; ++k) aan[k] = ap1[k];
    }
    {
      float ev[8]; float racc = 0.f;
      #pragma unroll
      for (int jj = 0; jj < 8; ++jj){
        float u = wb[jj];
        #pragma unroll
        for (int k = 0; k < 8; ++k) u = fmaf(aa[k], wa[k][jj], u);
        ev[jj] = __expf(u); racc += ev[jj];
      }
      *(float4*)&tile[0][lane * TS + jb]     = make_float4(ev[0],ev[1],ev[2],ev[3]);
      *(float4*)&tile[0][lane * TS + jb + 4] = make_float4(ev[4],ev[5],ev[6],ev[7]);
      rsp[0][pw][lane] = racc;
    }
    BARRIER();
    int tw = 1;
    for (int s = 0; s < TT - 1; ++s){
      if (s <= TT - 3){
        #pragma unroll
        for (int k = 0; k < 8; ++k) aa[k] = aan[k];
        if (s + 1 <= TT - 3){
          const int tn = is_fwd ? (s + 2) : (TT - 4 - s);
          #pragma unroll
          for (int k = 0; k < 8; ++k) aan[k] = aLDS[tn * AA + k];
        }
        float ev[8]; float racc = 0.f;
        #pragma unroll
        for (int jj = 0; jj < 8; ++jj){
          float u = wb[jj];
          #pragma unroll
          for (int k = 0; k < 8; ++k) u = fmaf(aa[k], wa[k][jj], u);
          ev[jj] = __expf(u); racc += ev[jj];
        }
        *(float4*)&tile[tw][lane * TS + jb]     = make_float4(ev[0],ev[1],ev[2],ev[3]);
        *(float4*)&tile[tw][lane * TS + jb + 4] = make_float4(ev[4],ev[5],ev[6],ev[7]);
        rsp[tw][pw][lane] = racc;
        tw = (tw == 2) ? 0 : tw + 1;
      }
      BARRIER();
    }
  } else if (is_fwd){
    const int wb16 = __builtin_amdgcn_readfirstlane(w * 16);
    float u = __expf(slx[b * SS + lane] + il[lane]);
    float c = __builtin_amdgcn_rcpf(wave_sum_dpp(u));
    if (w == 0) alpha[b * SS + lane] = u * c;
    float slxn = slx[(BB + b) * SS + lane];
    float elxc = 0.f;
    BARRIER();
    int ts = 0;
    for (int s = 0; s < TT - 1; ++s){
      if (s > 0){
        const int fs = (s - 1) & 1;
        float S = (fpart[fs][0][lane] + fpart[fs][1][lane])
                + (fpart[fs][2][lane] + fpart[fs][3][lane]);
        u = elxc * fmaf(c, S, SEPS);
        c = __builtin_amdgcn_rcpf(wave_sum_dpp(u));
        if (w == 0) alpha[(s * BB + b) * SS + lane] = u * c;
      }
      float rs = ((rsp[ts][0][lane] + rsp[ts][1][lane]) + (rsp[ts][2][lane] + rsp[ts][3][lane]))
               + ((rsp[ts][4][lane] + rsp[ts][5][lane]) + (rsp[ts][6][lane] + rsp[ts][7][lane]));
      float va = u * __builtin_amdgcn_rcpf(rs);
      const float* __restrict__ tp = &tile[ts][0];
      float a0 = 0.f, a1 = 0.f, a2 = 0.f, a3 = 0.f;
      #pragma unroll
      for (int r = 0; r < 16; r += 4){
        a0 = fmaf(readlane_f(va, wb16 + r    ), tp[(wb16 + r    ) * TS + lane], a0);
        a1 = fmaf(readlane_f(va, wb16 + r + 1), tp[(wb16 + r + 1) * TS + lane], a1);
        a2 = fmaf(readlane_f(va, wb16 + r + 2), tp[(wb16 + r + 2) * TS + lane], a2);
        a3 = fmaf(readlane_f(va, wb16 + r + 3), tp[(wb16 + r + 3) * TS + lane], a3);
      }
      fpart[s & 1][w][lane] = (a0 + a1) + (a2 + a3);
      elxc = __expf(slxn);
      if (s + 2 <= TT - 1) slxn = slx[((s + 2) * BB + b) * SS + lane];
      ts = (ts == 2) ? 0 : ts + 1;
      BARRIER();
    }
    {
      const int fs = (TT - 2) & 1;
      float S = (fpart[fs][0][lane] + fpart[fs][1][lane])
              + (fpart[fs][2][lane] + fpart[fs][3][lane]);
      u = elxc * fmaf(c, S, SEPS);
      c = __builtin_amdgcn_rcpf(wave_sum_dpp(u));
      if (w == 0) alpha[((TT - 1) * BB + b) * SS + lane] = u * c;
    }
  } else {
    const int wb16 = __builtin_amdgcn_readfirstlane(w * 16);
    float breg = 0.f, rWc = 1.f;
    if (w == 0) log_beta[((TT - 1) * BB + b) * SS + lane] = 0.f;
    float slxc = slx[((TT - 1) * BB + b) * SS + lane];
    float mprev = 1.f;
    BARRIER();
    int ts = 0, pts = 2;
    for (int s = 0; s < TT - 1; ++s){
      if (s > 0){
        const int fs = (s - 1) & 1;
        float eh = (fpart[fs][0][lane] + fpart[fs][1][lane])
                 + (fpart[fs][2][lane] + fpart[fs][3][lane]);
        float rsv = ((rsp[pts][0][lane] + rsp[pts][1][lane]) + (rsp[pts][2][lane] + rsp[pts][3][lane]))
                  + ((rsp[pts][4][lane] + rsp[pts][5][lane]) + (rsp[pts][6][lane] + rsp[pts][7][lane]));
        float v = __logf(fmaf(eh * __builtin_amdgcn_rcpf(rsv), rWc, EPSF));
        breg = (mprev == 1.0f) ? v : 0.0f;
        if (w == 0) log_beta[((TT - 1 - s) * BB + b) * SS + lane] = breg;
      }
      float wgt = __expf(slxc + breg);
      float W = wave_sum_dpp(wgt);
      rWc = __builtin_amdgcn_rcpf(W);
      const float* __restrict__ tp = &tile[ts][lane * TS + wb16];
      float4 e0 = *(const float4*)(tp);
      float4 e1 = *(const float4*)(tp + 4);
      float4 e2 = *(const float4*)(tp + 8);
      float4 e3 = *(const float4*)(tp + 12);
      float a0 = 0.f, a1 = 0.f, a2 = 0.f, a3 = 0.f;
      a0 = fmaf(readlane_f(wgt, wb16 + 0),  e0.x, a0);
      a1 = fmaf(readlane_f(wgt, wb16 + 1),  e0.y, a1);
      a2 = fmaf(readlane_f(wgt, wb16 + 2),  e0.z, a2);
      a3 = fmaf(readlane_f(wgt, wb16 + 3),  e0.w, a3);
      a0 = fmaf(readlane_f(wgt, wb16 + 4),  e1.x, a0);
      a1 = fmaf(readlane_f(wgt, wb16 + 5),  e1.y, a1);
      a2 = fmaf(readlane_f(wgt, wb16 + 6),  e1.z, a2);
      a3 = fmaf(readlane_f(wgt, wb16 + 7),  e1.w, a3);
      a0 = fmaf(readlane_f(wgt, wb16 + 8),  e2.x, a0);
      a1 = fmaf(readlane_f(wgt, wb16 + 9),  e2.y, a1);
      a2 = fmaf(readlane_f(wgt, wb16 + 10), e2.z, a2);
      a3 = fmaf(readlane_f(wgt, wb16 + 11), e2.w, a3);
      a0 = fmaf(readlane_f(wgt, wb16 + 12), e3.x, a0);
      a1 = fmaf(readlane_f(wgt, wb16 + 13), e3.y, a1);
      a2 = fmaf(readlane_f(wgt, wb16 + 14), e3.z, a2);
      a3 = fmaf(readlane_f(wgt, wb16 + 15), e3.w, a3);
      fpart[s & 1][w][lane] = (a0 + a1) + (a2 + a3);
      mprev = mLDS[TT - 1 - s];
      if (s <= TT - 3) slxc = slx[((TT - 2 - s) * BB + b) * SS + lane];
      pts = ts; ts = (ts == 2) ? 0 : ts + 1;
      BARRIER();
    }
    {
      const int fs = (TT - 2) & 1;
      float eh = (fpart[fs][0][lane] + fpart[fs][1][lane])
               + (fpart[fs][2][lane] + fpart[fs][3][lane]);
      float rsv = ((rsp[pts][0][lane] + rsp[pts][1][lane]) + (rsp[pts][2][lane] + rsp[pts][3][lane]))
                + ((rsp[pts][4][lane] + rsp[pts][5][lane]) + (rsp[pts][6][lane] + rsp[pts][7][lane]));
      float v = __logf(fmaf(eh * __builtin_amdgcn_rcpf(rsv), rWc, EPSF));
      breg = (mprev == 1.0f) ? v : 0.0f;
      if (w == 0) log_beta[b * SS + lane] = breg;
    }
  }
}

// --- kernel 3: q_z = softmax(log(alpha+EPS) + log_beta) over states
__global__ __launch_bounds__(256) void qz_kernel(
    const float* __restrict__ alpha, const float* __restrict__ log_beta,
    float* __restrict__ out){
  const int lane = threadIdx.x & 63;
  const int w = threadIdx.x >> 6;
  const int row = blockIdx.x * 4 + w;
  float v = __logf(alpha[row * SS + lane] + EPSF) + log_beta[row * SS + lane];
  float mx = wave_max(v);
  float e = __expf(v - mx);
  float sm = wave_sum(e);
  out[row * SS + lane] = e * __builtin_amdgcn_rcpf(sm);
}

extern "C" void kernel_launch(void* const* d_in, const int* in_sizes, int n_in,
                              void* d_out, int out_size, void* d_ws, size_t ws_size,
                              hipStream_t stream){
  const float* x      = (const float*)d_in[0];
  const float* a      = (const float*)d_in[1];
  const float* mask   = (const float*)d_in[2];
  const float* mu     = (const float*)d_in[3];
  const float* logv   = (const float*)d_in[4];
  const float* il     = (const float*)d_in[5];
  const float* w_base = (const float*)d_in[6];
  const float* w_act  = (const float*)d_in[7];
  float* out = (float*)d_out;

  float* ws = (float*)d_ws;
  const size_t TBS = (size_t)TT * BB * SS;
  float* slx      = ws + 4096;        // TBS (offset kept for layout stability)
  float* alpha    = slx + TBS;        // TBS
  float* log_beta = alpha + TBS;      // TBS
  unsigned short* trans = (unsigned short*)(log_beta + TBS); // fp16, col-interleaved

  // Full precompute: base (12.6 MB) + 511 slices x 256 KB = ~147 MB (fits).
  const size_t base_bytes = ((size_t)4096 + 3 * TBS) * 4;
  const size_t full_bytes = base_bytes + (size_t)(TT - 1) * BB * SS * SS * 2;

  logpx_kernel<<<TT * BB / 4, 256, 0, stream>>>(x, mu, logv, slx);
  if (ws_size >= full_bytes){
    trans_kernel<<<512, 512, 0, stream>>>(a, w_base, w_act, trans, TT - 1);
    scan_wave_kernel<<<2 * BB, 64, 0, stream>>>(slx, mask, il, trans,
                                                alpha, log_beta);
  } else {
    scan_kernel<<<2 * BB, 768, 0, stream>>>(slx, mask, il, a, w_base, w_act,
                                            alpha, log_beta);
  }
  qz_kernel<<<TT * BB / 4, 256, 0, stream>>>(alpha, log_beta, out);
}